// Round 6
// baseline (393.777 us; speedup 1.0000x reference)
//
#include <hip/hip_runtime.h>
#include <stdint.h>

typedef unsigned short u16;
typedef __attribute__((ext_vector_type(8))) short short8;
typedef __attribute__((ext_vector_type(4))) float f32x4;
typedef __attribute__((ext_vector_type(4))) unsigned short u16x4;

#define TOKENS 4096
#define E_DIM 1024
#define F_DIM 4096
#define SEQ 2048
#define NH 16
#define DH 64

__device__ __forceinline__ u16 f2b(float f) {
  union { float f; unsigned u; } v; v.f = f;
  unsigned r = v.u + 0x7fffu + ((v.u >> 16) & 1u);
  return (u16)(r >> 16);
}

__device__ __forceinline__ void gl2lds16(const u16* g, u16* l) {
  __builtin_amdgcn_global_load_lds(
      (const __attribute__((address_space(1))) unsigned int*)(size_t)(g),
      (__attribute__((address_space(3))) unsigned int*)(unsigned int)(size_t)(l),
      16, 0, 0);
}

// ---------------------------------------------------------------------------
__global__ __launch_bounds__(256)
void transpose_w(const float* __restrict__ W, u16* __restrict__ Wt, int K, int N) {
  __shared__ float tile[32][33];
  const int kb = blockIdx.x * 32, nb = blockIdx.y * 32;
  const int tx = threadIdx.x & 31, ty = threadIdx.x >> 5;  // 32 x 8
#pragma unroll
  for (int i = 0; i < 32; i += 8)
    tile[ty + i][tx] = W[(size_t)(kb + ty + i) * N + nb + tx];
  __syncthreads();
#pragma unroll
  for (int i = 0; i < 32; i += 8)
    Wt[(size_t)(nb + ty + i) * K + kb + tx] = f2b(tile[tx][ty + i]);
}

// ---------------------------------------------------------------------------
__global__ __launch_bounds__(256)
void f32_to_bf16(const float* __restrict__ in, u16* __restrict__ out) {
  const int i = blockIdx.x * 256 + threadIdx.x;
  f32x4 f = ((const f32x4*)in)[i];
  u16x4 u;
#pragma unroll
  for (int j = 0; j < 4; j++) u[j] = f2b(f[j]);
  ((u16x4*)out)[i] = u;
}

// ---------------------------------------------------------------------------
// v (token-major bf16) -> vt [B][H][DH][SEQ], with the key dimension
// sigma-permuted within each 64-key window: position p holds key
// sigma^{-1}(p) = (p&3)*16 + (p>>2). (PV contraction is key-permutation
// invariant when P and Vt use the same permutation; sigma makes attention's
// per-thread P quad contiguous -> one ds_write_b64 instead of 4 b16.)
// ---------------------------------------------------------------------------
__global__ __launch_bounds__(256)
void transpose_v(const u16* __restrict__ vsrc, u16* __restrict__ vt) {
  __shared__ u16 tile[64][66];
  const int kb = blockIdx.x * 64;  // 64-key window
  const int bh = blockIdx.y;
  const int b = bh >> 4, h = bh & 15;
  {
    const int d = threadIdx.x & 63, r = threadIdx.x >> 6;  // 64 x 4
#pragma unroll
    for (int i = 0; i < 64; i += 4)
      tile[r + i][d] = vsrc[(size_t)(b * SEQ + kb + r + i) * E_DIM + h * DH + d];
  }
  __syncthreads();
  {
    const int pos = threadIdx.x & 63;
    const int srck = (pos & 3) * 16 + (pos >> 2);  // sigma^{-1}(pos)
#pragma unroll
    for (int j = 0; j < 64; j += 4) {
      const int d = (threadIdx.x >> 6) + j;
      vt[(size_t)(bh * DH + d) * SEQ + kb + pos] = tile[srck][d];
    }
  }
}

// ---------------------------------------------------------------------------
// GEMM 128x128: C = A (MxK bf16) @ Bt^T (NxK bf16) + bias. m97 structure.
// ---------------------------------------------------------------------------
template <int RELU, int OUTBF>
__global__ __launch_bounds__(256)
void gemm_bt(const u16* __restrict__ A, const u16* __restrict__ Bt,
             const float* __restrict__ bias, void* __restrict__ Cout,
             int M, int N, int K) {
  __shared__ __align__(16) u16 As[128 * 32];
  __shared__ __align__(16) u16 Bs[128 * 32];
  const int tid = threadIdx.x;
  const int lane = tid & 63, wave = tid >> 6;
  const int mBlk = blockIdx.y * 128, nBlk = blockIdx.x * 128;
  const int wm = (wave >> 1) * 64, wn = (wave & 1) * 64;
  const int l15 = lane & 15, g = lane >> 4;

  f32x4 acc[4][4] = {};
  const int srow = lane >> 2;
  const int scol = (lane & 3) * 8;

  const u16* Ab = A + (size_t)mBlk * K;
  const u16* Bb = Bt + (size_t)nBlk * K;

  for (int k0 = 0; k0 < K; k0 += 32) {
    __syncthreads();
    for (int c = wave; c < 8; c += 4) {
      const int r = c * 16 + srow;
      gl2lds16(Ab + (size_t)r * K + k0 + scol, As + c * 512 + lane * 8);
      gl2lds16(Bb + (size_t)r * K + k0 + scol, Bs + c * 512 + lane * 8);
    }
    __syncthreads();

    short8 af[4], bf[4];
#pragma unroll
    for (int i = 0; i < 4; i++)
      af[i] = *(const short8*)(As + (wm + i * 16 + l15) * 32 + g * 8);
#pragma unroll
    for (int i = 0; i < 4; i++)
      bf[i] = *(const short8*)(Bs + (wn + i * 16 + l15) * 32 + g * 8);
#pragma unroll
    for (int mi = 0; mi < 4; mi++)
#pragma unroll
      for (int ni = 0; ni < 4; ni++)
        acc[mi][ni] = __builtin_amdgcn_mfma_f32_16x16x32_bf16(af[mi], bf[ni],
                                                              acc[mi][ni], 0, 0, 0);
  }

  const int row0 = mBlk + wm + g * 4;
  const int col0 = nBlk + wn + l15;
#pragma unroll
  for (int ni = 0; ni < 4; ni++) {
    const int c = col0 + ni * 16;
    const float bv = bias[c];
#pragma unroll
    for (int mi = 0; mi < 4; mi++) {
#pragma unroll
      for (int r = 0; r < 4; r++) {
        float v = acc[mi][ni][r] + bv;
        if (RELU) v = fmaxf(v, 0.f);
        const size_t idx = (size_t)(row0 + mi * 16 + r) * N + c;
        if (OUTBF) ((u16*)Cout)[idx] = f2b(v);
        else       ((float*)Cout)[idx] = v;
      }
    }
  }
}

// ---------------------------------------------------------------------------
// Split-K GEMM, 128x128 tile: blockIdx.z halves K. Partial kz writes fp32 to
// Cout + kz*M*N (contiguous partials); bias added by kz==0 only.
// ---------------------------------------------------------------------------
__global__ __launch_bounds__(256)
void gemm_bt_sk(const u16* __restrict__ A, const u16* __restrict__ Bt,
                const float* __restrict__ bias, float* __restrict__ Cout,
                int M, int N, int K) {
  __shared__ __align__(16) u16 As[128 * 32];
  __shared__ __align__(16) u16 Bs[128 * 32];
  const int tid = threadIdx.x;
  const int lane = tid & 63, wave = tid >> 6;
  const int mBlk = blockIdx.y * 128, nBlk = blockIdx.x * 128;
  const int kz = blockIdx.z;
  const int Kh = K >> 1;
  const int wm = (wave >> 1) * 64, wn = (wave & 1) * 64;
  const int l15 = lane & 15, g = lane >> 4;

  f32x4 acc[4][4] = {};
  const int srow = lane >> 2;
  const int scol = (lane & 3) * 8;

  const u16* Ab = A + (size_t)mBlk * K + (size_t)kz * Kh;
  const u16* Bb = Bt + (size_t)nBlk * K + (size_t)kz * Kh;

  for (int k0 = 0; k0 < Kh; k0 += 32) {
    __syncthreads();
    for (int c = wave; c < 8; c += 4) {
      const int r = c * 16 + srow;
      gl2lds16(Ab + (size_t)r * K + k0 + scol, As + c * 512 + lane * 8);
      gl2lds16(Bb + (size_t)r * K + k0 + scol, Bs + c * 512 + lane * 8);
    }
    __syncthreads();

    short8 af[4], bf[4];
#pragma unroll
    for (int i = 0; i < 4; i++)
      af[i] = *(const short8*)(As + (wm + i * 16 + l15) * 32 + g * 8);
#pragma unroll
    for (int i = 0; i < 4; i++)
      bf[i] = *(const short8*)(Bs + (wn + i * 16 + l15) * 32 + g * 8);
#pragma unroll
    for (int mi = 0; mi < 4; mi++)
#pragma unroll
      for (int ni = 0; ni < 4; ni++)
        acc[mi][ni] = __builtin_amdgcn_mfma_f32_16x16x32_bf16(af[mi], bf[ni],
                                                              acc[mi][ni], 0, 0, 0);
  }

  float* out = Cout + (size_t)kz * M * N;
  const int row0 = mBlk + wm + g * 4;
  const int col0 = nBlk + wn + l15;
#pragma unroll
  for (int ni = 0; ni < 4; ni++) {
    const int c = col0 + ni * 16;
    const float bv = (kz == 0) ? bias[c] : 0.f;
#pragma unroll
    for (int mi = 0; mi < 4; mi++) {
#pragma unroll
      for (int r = 0; r < 4; r++)
        out[(size_t)(row0 + mi * 16 + r) * N + c] = acc[mi][ni][r] + bv;
    }
  }
}

// ---------------------------------------------------------------------------
// Fused Q+V GEMM: Bqv = [WqT | WvT] contiguous (2048 x K). Q half scaled by
// 1/sqrt(Dh)=0.125 (folded so attention needn't scale scores). 1024 blocks.
// ---------------------------------------------------------------------------
__global__ __launch_bounds__(256)
void gemm_qv64(const u16* __restrict__ A, const u16* __restrict__ Bqv,
               const float* __restrict__ bq, const float* __restrict__ bv,
               u16* __restrict__ qout, u16* __restrict__ vout, int K) {
  __shared__ __align__(16) u16 As[128 * 32];
  __shared__ __align__(16) u16 Bs[64 * 32];
  const int tid = threadIdx.x;
  const int lane = tid & 63, wave = tid >> 6;
  const int mBlk = blockIdx.y * 128, nBlk = blockIdx.x * 64;
  const int isQ = nBlk < 1024;
  const int ncol = isQ ? nBlk : nBlk - 1024;
  const float* bias = isQ ? bq : bv;
  u16* out = isQ ? qout : vout;
  const float oscale = isQ ? 0.125f : 1.0f;
  const int wm = (wave >> 1) * 64, wn = (wave & 1) * 32;
  const int l15 = lane & 15, g = lane >> 4;

  f32x4 acc[4][2] = {};
  const int srow = lane >> 2;
  const int scol = (lane & 3) * 8;

  const u16* Ab = A + (size_t)mBlk * K;
  const u16* Bb = Bqv + (size_t)nBlk * K;

  for (int k0 = 0; k0 < K; k0 += 32) {
    __syncthreads();
    for (int c = wave; c < 8; c += 4) {
      const int r = c * 16 + srow;
      gl2lds16(Ab + (size_t)r * K + k0 + scol, As + c * 512 + lane * 8);
    }
    gl2lds16(Bb + (size_t)(wave * 16 + srow) * K + k0 + scol, Bs + wave * 512 + lane * 8);
    __syncthreads();

    short8 af[4], bf[2];
#pragma unroll
    for (int i = 0; i < 4; i++)
      af[i] = *(const short8*)(As + (wm + i * 16 + l15) * 32 + g * 8);
#pragma unroll
    for (int i = 0; i < 2; i++)
      bf[i] = *(const short8*)(Bs + (wn + i * 16 + l15) * 32 + g * 8);
#pragma unroll
    for (int mi = 0; mi < 4; mi++)
#pragma unroll
      for (int ni = 0; ni < 2; ni++)
        acc[mi][ni] = __builtin_amdgcn_mfma_f32_16x16x32_bf16(af[mi], bf[ni],
                                                              acc[mi][ni], 0, 0, 0);
  }

  const int row0 = mBlk + wm + g * 4;
  const int col0 = ncol + wn + l15;
#pragma unroll
  for (int ni = 0; ni < 2; ni++) {
    const int c = col0 + ni * 16;
    const float bv_ = bias[c];
#pragma unroll
    for (int mi = 0; mi < 4; mi++) {
#pragma unroll
      for (int r = 0; r < 4; r++) {
        float v = (acc[mi][ni][r] + bv_) * oscale;
        out[(size_t)(row0 + mi * 16 + r) * E_DIM + c] = f2b(v);
      }
    }
  }
}

// ---------------------------------------------------------------------------
// Flash attention v3: LDS-issue optimized.
// Block = 128 threads (2 waves), each wave 32 q (2 subtiles of 16) -> 64
// q/block, grid (SEQ/64, B*H) = 1024 blocks = 4/CU. KC=64.
// - V/Vt staged once per block via global_load_lds (XOR chunk swizzle).
// - B-fragments (Vs/Vts) shared across both q-subtiles: 20 ds_read_b128 per
//   wave-iter for 32 MFMAs (vs 36 per 32q before).
// - P keys sigma-permuted (matching vt) so each thread's 4 P values are
//   contiguous: one packed ds_write_b64 (v_perm) instead of 4 ds_write_b16.
// - P rows padded to 72 u16 (144B, 16B-aligned): all P traffic <=2-way bank
//   aliasing (free per m136) without any XOR.
// - No-max softmax (scores pre-scaled 1/8 in Q GEMM; |s| small); l-sum uses
//   the truncated-bf16 p so numerator/denominator bias cancels.
// ---------------------------------------------------------------------------
__global__ __launch_bounds__(128)
void attn_kernel(const u16* __restrict__ qb, const u16* __restrict__ vb,
                 const u16* __restrict__ vtb, u16* __restrict__ ctxb) {
  __shared__ __align__(16) u16 Vs[64 * 64];     // [key][d-chunk ^ (key&7)]
  __shared__ __align__(16) u16 Vts[64 * 64];    // [d][pos-chunk ^ (d&7)]
  __shared__ __align__(16) u16 Pl[2][32 * 72];  // per-wave P, padded rows
  const int tid = threadIdx.x;
  const int lane = tid & 63;
  const int wave = tid >> 6;
  const int l15 = lane & 15;
  const int g = lane >> 4;
  const int qblk = blockIdx.x;
  const int bh = blockIdx.y;
  const int b = bh >> 4;
  const int h = bh & 15;
  const int qrow = qblk * 64 + wave * 32;

  // Q A-frags, persistent: [subtile][kstep]
  short8 aq[2][2];
#pragma unroll
  for (int sub = 0; sub < 2; sub++) {
    const u16* qp = qb + ((size_t)(b * SEQ + qrow + sub * 16 + l15)) * E_DIM + h * DH + g * 8;
    aq[sub][0] = *(const short8*)(qp);
    aq[sub][1] = *(const short8*)(qp + 32);
  }

  f32x4 o[2][4] = {};
  float lsum[2][4] = {};

  const u16* vbase = vb + ((size_t)b * SEQ) * E_DIM + h * DH;
  const u16* vtbase = vtb + ((size_t)bh * DH) * SEQ;
  u16* myPl = Pl[wave];

  const int srow = tid >> 3;  // 0..15
  const int sch = tid & 7;    // 0..7 (16B chunk)

  for (int kc = 0; kc < SEQ; kc += 64) {
    __syncthreads();
#pragma unroll
    for (int j = 0; j < 4; j++) {
      const int key = j * 16 + srow;
      gl2lds16(vbase + (size_t)(kc + key) * E_DIM + ((sch ^ (key & 7)) * 8),
               Vs + key * 64 + sch * 8);
      const int d = j * 16 + srow;
      gl2lds16(vtbase + (size_t)d * SEQ + kc + ((sch ^ (d & 7)) * 8),
               Vts + d * 64 + sch * 8);
    }
    __syncthreads();

    // S-tiles: 32 q x 64 keys; B-frags shared across the two q-subtiles
    f32x4 s[2][4];
#pragma unroll
    for (int nt = 0; nt < 4; nt++) {
      const int key = nt * 16 + l15;
      const u16* vr = Vs + key * 64;
      short8 b0 = *(const short8*)(vr + ((g ^ (key & 7)) * 8));
      short8 b1 = *(const short8*)(vr + (((4 + g) ^ (key & 7)) * 8));
      f32x4 z0 = {}, z1 = {};
      z0 = __builtin_amdgcn_mfma_f32_16x16x32_bf16(aq[0][0], b0, z0, 0, 0, 0);
      z0 = __builtin_amdgcn_mfma_f32_16x16x32_bf16(aq[0][1], b1, z0, 0, 0, 0);
      z1 = __builtin_amdgcn_mfma_f32_16x16x32_bf16(aq[1][0], b0, z1, 0, 0, 0);
      z1 = __builtin_amdgcn_mfma_f32_16x16x32_bf16(aq[1][1], b1, z1, 0, 0, 0);
      s[0][nt] = z0;
      s[1][nt] = z1;
    }

    // p = exp(s); pack 4 truncated-bf16 per row-quad -> one b64 store.
    // sigma: key nt*16+l15 -> pos l15*4+nt, so quad sits at u16 offset l15*4.
#pragma unroll
    for (int sub = 0; sub < 2; sub++) {
#pragma unroll
      for (int r = 0; r < 4; r++) {
        union { float f; unsigned u; } p0, p1, p2, p3;
        p0.f = __expf(s[sub][0][r]);
        p1.f = __expf(s[sub][1][r]);
        p2.f = __expf(s[sub][2][r]);
        p3.f = __expf(s[sub][3][r]);
        union { unsigned u; float f; } t0, t1, t2, t3;
        t0.u = p0.u & 0xffff0000u;
        t1.u = p1.u & 0xffff0000u;
        t2.u = p2.u & 0xffff0000u;
        t3.u = p3.u & 0xffff0000u;
        lsum[sub][r] += (t0.f + t1.f) + (t2.f + t3.f);
        uint2 pk;
        pk.x = __builtin_amdgcn_perm(p1.u, p0.u, 0x07060302u);
        pk.y = __builtin_amdgcn_perm(p3.u, p2.u, 0x07060302u);
        *(uint2*)(myPl + (sub * 16 + g * 4 + r) * 72 + l15 * 4) = pk;
      }
    }

    // PV: 2 k-steps of 32 positions; Vt B-frags shared across subtiles.
#pragma unroll
    for (int ks = 0; ks < 2; ks++) {
      short8 ap0 = *(const short8*)(myPl + (l15) * 72 + ks * 32 + g * 8);
      short8 ap1 = *(const short8*)(myPl + (16 + l15) * 72 + ks * 32 + g * 8);
#pragma unroll
      for (int dt = 0; dt < 4; dt++) {
        const int d = dt * 16 + l15;
        short8 bv = *(const short8*)(Vts + d * 64 + (((ks * 4 + g) ^ (d & 7)) * 8));
        o[0][dt] = __builtin_amdgcn_mfma_f32_16x16x32_bf16(ap0, bv, o[0][dt], 0, 0, 0);
        o[1][dt] = __builtin_amdgcn_mfma_f32_16x16x32_bf16(ap1, bv, o[1][dt], 0, 0, 0);
      }
    }
  }

#pragma unroll
  for (int sub = 0; sub < 2; sub++) {
#pragma unroll
    for (int r = 0; r < 4; r++) {
      float l = lsum[sub][r];
      l += __shfl_xor(l, 1);
      l += __shfl_xor(l, 2);
      l += __shfl_xor(l, 4);
      l += __shfl_xor(l, 8);
      const float inv = 1.0f / l;
      size_t base = ((size_t)(b * SEQ + qrow + sub * 16 + g * 4 + r)) * E_DIM + h * DH;
#pragma unroll
      for (int dt = 0; dt < 4; dt++)
        ctxb[base + dt * 16 + l15] = f2b(o[sub][dt][r] * inv);
    }
  }
}

// ---------------------------------------------------------------------------
// out = LayerNorm(X + Y0 + Y1); Y0/Y1 = split-K partials. In-place safe when
// out32 aliases an input (each thread reads its own row elements first).
// ---------------------------------------------------------------------------
__global__ __launch_bounds__(256)
void add_ln3(const float* __restrict__ X, const float* __restrict__ Y0,
             const float* __restrict__ Y1,
             const float* __restrict__ gam, const float* __restrict__ bet,
             float* __restrict__ out32, u16* __restrict__ out16) {
  const int row = blockIdx.x;
  const int tid = threadIdx.x;
  const size_t base = (size_t)row * E_DIM;
  float v[4];
  float s = 0.f, sq = 0.f;
#pragma unroll
  for (int i = 0; i < 4; i++) {
    const int c = tid + i * 256;
    float x = X[base + c] + Y0[base + c] + Y1[base + c];
    v[i] = x; s += x; sq += x * x;
  }
#pragma unroll
  for (int off = 32; off; off >>= 1) {
    s += __shfl_xor(s, off);
    sq += __shfl_xor(sq, off);
  }
  __shared__ float sh[8];
  const int wave = tid >> 6, lane = tid & 63;
  if (lane == 0) { sh[wave] = s; sh[4 + wave] = sq; }
  __syncthreads();
  s = sh[0] + sh[1] + sh[2] + sh[3];
  sq = sh[4] + sh[5] + sh[6] + sh[7];
  const float mean = s * (1.f / 1024.f);
  const float var = sq * (1.f / 1024.f) - mean * mean;
  const float rstd = rsqrtf(var + 1e-5f);
#pragma unroll
  for (int i = 0; i < 4; i++) {
    const int c = tid + i * 256;
    float y = (v[i] - mean) * rstd * gam[c] + bet[c];
    out32[base + c] = y;
    if (out16) out16[base + c] = f2b(y);
  }
}

// ---------------------------------------------------------------------------
extern "C" void kernel_launch(void* const* d_in, const int* in_sizes, int n_in,
                              void* d_out, int out_size, void* d_ws, size_t ws_size,
                              hipStream_t stream) {
  const float* x   = (const float*)d_in[0];
  const float* Wq  = (const float*)d_in[1];
  const float* bq  = (const float*)d_in[2];
  // d_in[3]=Wk, d_in[4]=bk -- dead code in the reference (scores use Q@V^T)
  const float* Wv  = (const float*)d_in[5];
  const float* bv  = (const float*)d_in[6];
  const float* Wo  = (const float*)d_in[7];
  const float* bo  = (const float*)d_in[8];
  const float* g1  = (const float*)d_in[9];
  const float* b1  = (const float*)d_in[10];
  const float* W1  = (const float*)d_in[11];
  const float* bf1 = (const float*)d_in[12];
  const float* W2  = (const float*)d_in[13];
  const float* bf2 = (const float*)d_in[14];
  const float* g2  = (const float*)d_in[15];
  const float* b2  = (const float*)d_in[16];

  char* w = (char*)d_ws;
  const size_t MB = 1024ull * 1024ull;
  u16*   xb   = (u16*)(w + 0);          //  8MB
  u16*   h1   = (u16*)(w + 8 * MB);     // 32MB
  u16*   qb   = (u16*)(w + 8 * MB);     //  8MB
  u16*   vb   = (u16*)(w + 16 * MB);    //  8MB
  u16*   vtb  = (u16*)(w + 24 * MB);    //  8MB
  u16*   ctxb = (u16*)(w + 32 * MB);    //  8MB
  float* att0 = (float*)(w + 40 * MB);  // 32MB (both Wo partials, contiguous)
  float* ff0  = (float*)(w + 40 * MB);  // 32MB (both FF2 partials, contiguous)
  float* pa   = (float*)(w + 72 * MB);  // 16MB
  u16*   pab  = (u16*)(w + 88 * MB);    //  8MB
  u16*   WqT  = (u16*)(w + 96 * MB);    //  2MB (WqT|WvT contiguous)
  u16*   WvT  = (u16*)(w + 98 * MB);    //  2MB
  u16*   WoT  = (u16*)(w + 100 * MB);   //  2MB
  u16*   W1T  = (u16*)(w + 102 * MB);   //  8MB
  u16*   W2T  = (u16*)(w + 110 * MB);   //  8MB -> 118MB total

  transpose_w<<<dim3(32, 32), 256, 0, stream>>>(Wq, WqT, 1024, 1024);
  transpose_w<<<dim3(32, 32), 256, 0, stream>>>(Wv, WvT, 1024, 1024);
  transpose_w<<<dim3(32, 32), 256, 0, stream>>>(Wo, WoT, 1024, 1024);
  transpose_w<<<dim3(32, 128), 256, 0, stream>>>(W1, W1T, 1024, 4096);
  transpose_w<<<dim3(128, 32), 256, 0, stream>>>(W2, W2T, 4096, 1024);
  f32_to_bf16<<<TOKENS * E_DIM / 4 / 256, 256, 0, stream>>>(x, xb);

  gemm_qv64<<<dim3(32, 32), 256, 0, stream>>>(xb, WqT, bq, bv, qb, vb, 1024);
  transpose_v<<<dim3(32, 32), 256, 0, stream>>>(vb, vtb);
  attn_kernel<<<dim3(32, 32), 128, 0, stream>>>(qb, vb, vtb, ctxb);
  gemm_bt_sk<<<dim3(8, 32, 2), 256, 0, stream>>>(ctxb, WoT, bo, att0, TOKENS, 1024, 1024);
  add_ln3<<<TOKENS, 256, 0, stream>>>(x, att0, att0 + (size_t)TOKENS * 1024, g1, b1, pa, pab);
  gemm_bt<1, 1><<<dim3(32, 32), 256, 0, stream>>>(pab, W1T, bf1, h1, TOKENS, 4096, 1024);
  gemm_bt_sk<<<dim3(8, 32, 2), 256, 0, stream>>>(h1, W2T, bf2, ff0, TOKENS, 1024, 4096);
  add_ln3<<<TOKENS, 256, 0, stream>>>(pa, ff0, ff0 + (size_t)TOKENS * 1024, g2, b2, (float*)d_out, (u16*)nullptr);
}

// Round 7
// 380.682 us; speedup vs baseline: 1.0344x; 1.0344x over previous
//
#include <hip/hip_runtime.h>
#include <stdint.h>

typedef unsigned short u16;
typedef __attribute__((ext_vector_type(8))) short short8;
typedef __attribute__((ext_vector_type(4))) float f32x4;
typedef __attribute__((ext_vector_type(4))) unsigned short u16x4;

#define TOKENS 4096
#define E_DIM 1024
#define F_DIM 4096
#define SEQ 2048
#define NH 16
#define DH 64

__device__ __forceinline__ u16 f2b(float f) {
  union { float f; unsigned u; } v; v.f = f;
  unsigned r = v.u + 0x7fffu + ((v.u >> 16) & 1u);
  return (u16)(r >> 16);
}

__device__ __forceinline__ void gl2lds16(const u16* g, u16* l) {
  __builtin_amdgcn_global_load_lds(
      (const __attribute__((address_space(1))) unsigned int*)(size_t)(g),
      (__attribute__((address_space(3))) unsigned int*)(unsigned int)(size_t)(l),
      16, 0, 0);
}

// ---------------------------------------------------------------------------
__global__ __launch_bounds__(256)
void transpose_w(const float* __restrict__ W, u16* __restrict__ Wt, int K, int N) {
  __shared__ float tile[32][33];
  const int kb = blockIdx.x * 32, nb = blockIdx.y * 32;
  const int tx = threadIdx.x & 31, ty = threadIdx.x >> 5;  // 32 x 8
#pragma unroll
  for (int i = 0; i < 32; i += 8)
    tile[ty + i][tx] = W[(size_t)(kb + ty + i) * N + nb + tx];
  __syncthreads();
#pragma unroll
  for (int i = 0; i < 32; i += 8)
    Wt[(size_t)(nb + ty + i) * K + kb + tx] = f2b(tile[tx][ty + i]);
}

// ---------------------------------------------------------------------------
__global__ __launch_bounds__(256)
void f32_to_bf16(const float* __restrict__ in, u16* __restrict__ out) {
  const int i = blockIdx.x * 256 + threadIdx.x;
  f32x4 f = ((const f32x4*)in)[i];
  u16x4 u;
#pragma unroll
  for (int j = 0; j < 4; j++) u[j] = f2b(f[j]);
  ((u16x4*)out)[i] = u;
}

// ---------------------------------------------------------------------------
// v (token-major bf16) -> vt [B][H][DH][SEQ], key dimension sigma-permuted
// within each 64-key window: position p holds key (p&3)*16 + (p>>2).
// ---------------------------------------------------------------------------
__global__ __launch_bounds__(256)
void transpose_v(const u16* __restrict__ vsrc, u16* __restrict__ vt) {
  __shared__ u16 tile[64][66];
  const int kb = blockIdx.x * 64;
  const int bh = blockIdx.y;
  const int b = bh >> 4, h = bh & 15;
  {
    const int d = threadIdx.x & 63, r = threadIdx.x >> 6;  // 64 x 4
#pragma unroll
    for (int i = 0; i < 64; i += 4)
      tile[r + i][d] = vsrc[(size_t)(b * SEQ + kb + r + i) * E_DIM + h * DH + d];
  }
  __syncthreads();
  {
    const int pos = threadIdx.x & 63;
    const int srck = (pos & 3) * 16 + (pos >> 2);  // sigma^{-1}(pos)
#pragma unroll
    for (int j = 0; j < 64; j += 4) {
      const int d = (threadIdx.x >> 6) + j;
      vt[(size_t)(bh * DH + d) * SEQ + kb + pos] = tile[srck][d];
    }
  }
}

// ---------------------------------------------------------------------------
// GEMM 128x128: C = A (MxK bf16) @ Bt^T (NxK bf16) + bias. m97 structure.
// ---------------------------------------------------------------------------
template <int RELU, int OUTBF>
__global__ __launch_bounds__(256)
void gemm_bt(const u16* __restrict__ A, const u16* __restrict__ Bt,
             const float* __restrict__ bias, void* __restrict__ Cout,
             int M, int N, int K) {
  __shared__ __align__(16) u16 As[128 * 32];
  __shared__ __align__(16) u16 Bs[128 * 32];
  const int tid = threadIdx.x;
  const int lane = tid & 63, wave = tid >> 6;
  const int mBlk = blockIdx.y * 128, nBlk = blockIdx.x * 128;
  const int wm = (wave >> 1) * 64, wn = (wave & 1) * 64;
  const int l15 = lane & 15, g = lane >> 4;

  f32x4 acc[4][4] = {};
  const int srow = lane >> 2;
  const int scol = (lane & 3) * 8;

  const u16* Ab = A + (size_t)mBlk * K;
  const u16* Bb = Bt + (size_t)nBlk * K;

  for (int k0 = 0; k0 < K; k0 += 32) {
    __syncthreads();
    for (int c = wave; c < 8; c += 4) {
      const int r = c * 16 + srow;
      gl2lds16(Ab + (size_t)r * K + k0 + scol, As + c * 512 + lane * 8);
      gl2lds16(Bb + (size_t)r * K + k0 + scol, Bs + c * 512 + lane * 8);
    }
    __syncthreads();

    short8 af[4], bf[4];
#pragma unroll
    for (int i = 0; i < 4; i++)
      af[i] = *(const short8*)(As + (wm + i * 16 + l15) * 32 + g * 8);
#pragma unroll
    for (int i = 0; i < 4; i++)
      bf[i] = *(const short8*)(Bs + (wn + i * 16 + l15) * 32 + g * 8);
#pragma unroll
    for (int mi = 0; mi < 4; mi++)
#pragma unroll
      for (int ni = 0; ni < 4; ni++)
        acc[mi][ni] = __builtin_amdgcn_mfma_f32_16x16x32_bf16(af[mi], bf[ni],
                                                              acc[mi][ni], 0, 0, 0);
  }

  const int row0 = mBlk + wm + g * 4;
  const int col0 = nBlk + wn + l15;
#pragma unroll
  for (int ni = 0; ni < 4; ni++) {
    const int c = col0 + ni * 16;
    const float bv = bias[c];
#pragma unroll
    for (int mi = 0; mi < 4; mi++) {
#pragma unroll
      for (int r = 0; r < 4; r++) {
        float v = acc[mi][ni][r] + bv;
        if (RELU) v = fmaxf(v, 0.f);
        const size_t idx = (size_t)(row0 + mi * 16 + r) * N + c;
        if (OUTBF) ((u16*)Cout)[idx] = f2b(v);
        else       ((float*)Cout)[idx] = v;
      }
    }
  }
}

// ---------------------------------------------------------------------------
// Split-K GEMM, 128x128 tile: blockIdx.z halves K. Partial kz writes fp32 to
// Cout + kz*M*N (contiguous partials); bias added by kz==0 only.
// ---------------------------------------------------------------------------
__global__ __launch_bounds__(256)
void gemm_bt_sk(const u16* __restrict__ A, const u16* __restrict__ Bt,
                const float* __restrict__ bias, float* __restrict__ Cout,
                int M, int N, int K) {
  __shared__ __align__(16) u16 As[128 * 32];
  __shared__ __align__(16) u16 Bs[128 * 32];
  const int tid = threadIdx.x;
  const int lane = tid & 63, wave = tid >> 6;
  const int mBlk = blockIdx.y * 128, nBlk = blockIdx.x * 128;
  const int kz = blockIdx.z;
  const int Kh = K >> 1;
  const int wm = (wave >> 1) * 64, wn = (wave & 1) * 64;
  const int l15 = lane & 15, g = lane >> 4;

  f32x4 acc[4][4] = {};
  const int srow = lane >> 2;
  const int scol = (lane & 3) * 8;

  const u16* Ab = A + (size_t)mBlk * K + (size_t)kz * Kh;
  const u16* Bb = Bt + (size_t)nBlk * K + (size_t)kz * Kh;

  for (int k0 = 0; k0 < Kh; k0 += 32) {
    __syncthreads();
    for (int c = wave; c < 8; c += 4) {
      const int r = c * 16 + srow;
      gl2lds16(Ab + (size_t)r * K + k0 + scol, As + c * 512 + lane * 8);
      gl2lds16(Bb + (size_t)r * K + k0 + scol, Bs + c * 512 + lane * 8);
    }
    __syncthreads();

    short8 af[4], bf[4];
#pragma unroll
    for (int i = 0; i < 4; i++)
      af[i] = *(const short8*)(As + (wm + i * 16 + l15) * 32 + g * 8);
#pragma unroll
    for (int i = 0; i < 4; i++)
      bf[i] = *(const short8*)(Bs + (wn + i * 16 + l15) * 32 + g * 8);
#pragma unroll
    for (int mi = 0; mi < 4; mi++)
#pragma unroll
      for (int ni = 0; ni < 4; ni++)
        acc[mi][ni] = __builtin_amdgcn_mfma_f32_16x16x32_bf16(af[mi], bf[ni],
                                                              acc[mi][ni], 0, 0, 0);
  }

  float* out = Cout + (size_t)kz * M * N;
  const int row0 = mBlk + wm + g * 4;
  const int col0 = nBlk + wn + l15;
#pragma unroll
  for (int ni = 0; ni < 4; ni++) {
    const int c = col0 + ni * 16;
    const float bv = (kz == 0) ? bias[c] : 0.f;
#pragma unroll
    for (int mi = 0; mi < 4; mi++) {
#pragma unroll
      for (int r = 0; r < 4; r++)
        out[(size_t)(row0 + mi * 16 + r) * N + c] = acc[mi][ni][r] + bv;
    }
  }
}

// ---------------------------------------------------------------------------
// Fused Q+V GEMM: Bqv = [WqT | WvT] contiguous (2048 x K). Q half scaled by
// 1/sqrt(Dh)=0.125 (folded so attention needn't scale scores). 1024 blocks.
// ---------------------------------------------------------------------------
__global__ __launch_bounds__(256)
void gemm_qv64(const u16* __restrict__ A, const u16* __restrict__ Bqv,
               const float* __restrict__ bq, const float* __restrict__ bv,
               u16* __restrict__ qout, u16* __restrict__ vout, int K) {
  __shared__ __align__(16) u16 As[128 * 32];
  __shared__ __align__(16) u16 Bs[64 * 32];
  const int tid = threadIdx.x;
  const int lane = tid & 63, wave = tid >> 6;
  const int mBlk = blockIdx.y * 128, nBlk = blockIdx.x * 64;
  const int isQ = nBlk < 1024;
  const int ncol = isQ ? nBlk : nBlk - 1024;
  const float* bias = isQ ? bq : bv;
  u16* out = isQ ? qout : vout;
  const float oscale = isQ ? 0.125f : 1.0f;
  const int wm = (wave >> 1) * 64, wn = (wave & 1) * 32;
  const int l15 = lane & 15, g = lane >> 4;

  f32x4 acc[4][2] = {};
  const int srow = lane >> 2;
  const int scol = (lane & 3) * 8;

  const u16* Ab = A + (size_t)mBlk * K;
  const u16* Bb = Bqv + (size_t)nBlk * K;

  for (int k0 = 0; k0 < K; k0 += 32) {
    __syncthreads();
    for (int c = wave; c < 8; c += 4) {
      const int r = c * 16 + srow;
      gl2lds16(Ab + (size_t)r * K + k0 + scol, As + c * 512 + lane * 8);
    }
    gl2lds16(Bb + (size_t)(wave * 16 + srow) * K + k0 + scol, Bs + wave * 512 + lane * 8);
    __syncthreads();

    short8 af[4], bf[2];
#pragma unroll
    for (int i = 0; i < 4; i++)
      af[i] = *(const short8*)(As + (wm + i * 16 + l15) * 32 + g * 8);
#pragma unroll
    for (int i = 0; i < 2; i++)
      bf[i] = *(const short8*)(Bs + (wn + i * 16 + l15) * 32 + g * 8);
#pragma unroll
    for (int mi = 0; mi < 4; mi++)
#pragma unroll
      for (int ni = 0; ni < 2; ni++)
        acc[mi][ni] = __builtin_amdgcn_mfma_f32_16x16x32_bf16(af[mi], bf[ni],
                                                              acc[mi][ni], 0, 0, 0);
  }

  const int row0 = mBlk + wm + g * 4;
  const int col0 = ncol + wn + l15;
#pragma unroll
  for (int ni = 0; ni < 2; ni++) {
    const int c = col0 + ni * 16;
    const float bv_ = bias[c];
#pragma unroll
    for (int mi = 0; mi < 4; mi++) {
#pragma unroll
      for (int r = 0; r < 4; r++) {
        float v = (acc[mi][ni][r] + bv_) * oscale;
        out[(size_t)(row0 + mi * 16 + r) * E_DIM + c] = f2b(v);
      }
    }
  }
}

// ---------------------------------------------------------------------------
// Flash attention v4: double-buffered staging with raw s_barrier + fine
// s_waitcnt vmcnt(8) so prefetch loads stay in flight across the barrier
// (AITER-style; the compiler's __syncthreads would drain vmcnt(0)).
// Block = 128 threads (2 waves), 32 q/wave (2 subtiles), 64 q/block,
// grid (SEQ/64, B*H) = 1024 blocks = 4/CU. KC=64.
// Correctness of the barrier pair per iter:
//   barrier A: all waves finished READING buf[nxt] (they read it last iter,
//              and their reads complete before they reach this barrier);
//              only after A does anyone overwrite buf[nxt].
//   stage(buf[nxt]): 8 global_load_lds per thread, fly during compute.
//   s_waitcnt vmcnt(8): my 8 older loads (into buf[cur]) are done.
//   barrier B: everyone's buf[cur] loads are done -> safe to read buf[cur].
// P: sigma-permuted keys (matches transpose_v), packed b64 stores, XOR chunk
// swizzle, 64-u16 rows. LDS: 2*8 + 2*8 + 8 = 40KB -> 4 blocks/CU exactly.
// ---------------------------------------------------------------------------
__global__ __launch_bounds__(128)
void attn_kernel(const u16* __restrict__ qb, const u16* __restrict__ vb,
                 const u16* __restrict__ vtb, u16* __restrict__ ctxb) {
  __shared__ __align__(16) u16 Vs[2][64 * 64];   // [key][d-chunk ^ (key&7)]
  __shared__ __align__(16) u16 Vts[2][64 * 64];  // [d][pos-chunk ^ (d&7)]
  __shared__ __align__(16) u16 Pl[2][32 * 64];   // per-wave P, XOR swizzled
  const int tid = threadIdx.x;
  const int lane = tid & 63;
  const int wave = tid >> 6;
  const int l15 = lane & 15;
  const int g = lane >> 4;
  const int qblk = blockIdx.x;
  const int bh = blockIdx.y;
  const int b = bh >> 4;
  const int h = bh & 15;
  const int qrow = qblk * 64 + wave * 32;

  short8 aq[2][2];
#pragma unroll
  for (int sub = 0; sub < 2; sub++) {
    const u16* qp = qb + ((size_t)(b * SEQ + qrow + sub * 16 + l15)) * E_DIM + h * DH + g * 8;
    aq[sub][0] = *(const short8*)(qp);
    aq[sub][1] = *(const short8*)(qp + 32);
  }

  f32x4 o[2][4] = {};
  float lsum[2][4] = {};

  const u16* vbase = vb + ((size_t)b * SEQ) * E_DIM + h * DH;
  const u16* vtbase = vtb + ((size_t)bh * DH) * SEQ;
  u16* myPl = Pl[wave];

  const int srow = tid >> 3;  // 0..15
  const int sch = tid & 7;    // 0..7 (16B chunk)

  // stage one KC=64 window into buffer `buf` (8 loads/thread)
#define STAGE(buf, kcv)                                                          \
  {                                                                              \
    const int kc_ = (kcv);                                                       \
    _Pragma("unroll") for (int j = 0; j < 4; j++) {                              \
      const int key = j * 16 + srow;                                             \
      gl2lds16(vbase + (size_t)(kc_ + key) * E_DIM + ((sch ^ (key & 7)) * 8),    \
               Vs[buf] + key * 64 + sch * 8);                                    \
      const int d = j * 16 + srow;                                               \
      gl2lds16(vtbase + (size_t)d * SEQ + kc_ + ((sch ^ (d & 7)) * 8),           \
               Vts[buf] + d * 64 + sch * 8);                                     \
    }                                                                            \
  }

  STAGE(0, 0)
  int cur = 0;

  for (int kc = 0; kc < SEQ; kc += 64) {
    asm volatile("s_barrier" ::: "memory");  // A: readers of buf[nxt] done
    if (kc + 64 < SEQ) {
      STAGE(cur ^ 1, kc + 64)
      asm volatile("s_waitcnt vmcnt(8)" ::: "memory");
    } else {
      asm volatile("s_waitcnt vmcnt(0)" ::: "memory");
    }
    asm volatile("s_barrier" ::: "memory");  // B: everyone's buf[cur] loaded

    const u16* VsC = Vs[cur];
    const u16* VtsC = Vts[cur];

    // S-tiles: 32 q x 64 keys; B-frags shared across the two q-subtiles
    f32x4 s[2][4];
#pragma unroll
    for (int nt = 0; nt < 4; nt++) {
      const int key = nt * 16 + l15;
      const u16* vr = VsC + key * 64;
      short8 b0 = *(const short8*)(vr + ((g ^ (key & 7)) * 8));
      short8 b1 = *(const short8*)(vr + (((4 + g) ^ (key & 7)) * 8));
      f32x4 z0 = {}, z1 = {};
      z0 = __builtin_amdgcn_mfma_f32_16x16x32_bf16(aq[0][0], b0, z0, 0, 0, 0);
      z0 = __builtin_amdgcn_mfma_f32_16x16x32_bf16(aq[0][1], b1, z0, 0, 0, 0);
      z1 = __builtin_amdgcn_mfma_f32_16x16x32_bf16(aq[1][0], b0, z1, 0, 0, 0);
      z1 = __builtin_amdgcn_mfma_f32_16x16x32_bf16(aq[1][1], b1, z1, 0, 0, 0);
      s[0][nt] = z0;
      s[1][nt] = z1;
    }

    // p = exp(s); pack 4 truncated-bf16 -> one b64 store per row.
    // sigma: key nt*16+l15 -> pos l15*4+nt; quad at logical chunk l15>>1,
    // half (l15&1); phys chunk = (l15>>1) ^ (row&7).
#pragma unroll
    for (int sub = 0; sub < 2; sub++) {
#pragma unroll
      for (int r = 0; r < 4; r++) {
        const int row = sub * 16 + g * 4 + r;
        union { float f; unsigned u; } p0, p1, p2, p3;
        p0.f = __expf(s[sub][0][r]);
        p1.f = __expf(s[sub][1][r]);
        p2.f = __expf(s[sub][2][r]);
        p3.f = __expf(s[sub][3][r]);
        union { unsigned u; float f; } t0, t1, t2, t3;
        t0.u = p0.u & 0xffff0000u;
        t1.u = p1.u & 0xffff0000u;
        t2.u = p2.u & 0xffff0000u;
        t3.u = p3.u & 0xffff0000u;
        lsum[sub][r] += (t0.f + t1.f) + (t2.f + t3.f);
        uint2 pk;
        pk.x = __builtin_amdgcn_perm(p1.u, p0.u, 0x07060302u);
        pk.y = __builtin_amdgcn_perm(p3.u, p2.u, 0x07060302u);
        *(uint2*)(myPl + row * 64 + (((l15 >> 1) ^ (row & 7)) << 3) + ((l15 & 1) << 2)) = pk;
      }
    }

    // PV: 2 k-steps of 32 positions; Vt B-frags shared across subtiles.
#pragma unroll
    for (int ks = 0; ks < 2; ks++) {
      const int row0_ = l15, row1_ = 16 + l15;
      short8 ap0 = *(const short8*)(myPl + row0_ * 64 + (((ks * 4 + g) ^ (row0_ & 7)) << 3));
      short8 ap1 = *(const short8*)(myPl + row1_ * 64 + (((ks * 4 + g) ^ (row1_ & 7)) << 3));
#pragma unroll
      for (int dt = 0; dt < 4; dt++) {
        const int d = dt * 16 + l15;
        short8 bv = *(const short8*)(VtsC + d * 64 + (((ks * 4 + g) ^ (d & 7)) * 8));
        o[0][dt] = __builtin_amdgcn_mfma_f32_16x16x32_bf16(ap0, bv, o[0][dt], 0, 0, 0);
        o[1][dt] = __builtin_amdgcn_mfma_f32_16x16x32_bf16(ap1, bv, o[1][dt], 0, 0, 0);
      }
    }
    cur ^= 1;
  }
#undef STAGE

#pragma unroll
  for (int sub = 0; sub < 2; sub++) {
#pragma unroll
    for (int r = 0; r < 4; r++) {
      float l = lsum[sub][r];
      l += __shfl_xor(l, 1);
      l += __shfl_xor(l, 2);
      l += __shfl_xor(l, 4);
      l += __shfl_xor(l, 8);
      const float inv = 1.0f / l;
      size_t base = ((size_t)(b * SEQ + qrow + sub * 16 + g * 4 + r)) * E_DIM + h * DH;
#pragma unroll
      for (int dt = 0; dt < 4; dt++)
        ctxb[base + dt * 16 + l15] = f2b(o[sub][dt][r] * inv);
    }
  }
}

// ---------------------------------------------------------------------------
// out = LayerNorm(X + Y0 + Y1); Y0/Y1 = split-K partials. In-place safe when
// out32 aliases an input (each thread reads its own row elements first).
// ---------------------------------------------------------------------------
__global__ __launch_bounds__(256)
void add_ln3(const float* __restrict__ X, const float* __restrict__ Y0,
             const float* __restrict__ Y1,
             const float* __restrict__ gam, const float* __restrict__ bet,
             float* __restrict__ out32, u16* __restrict__ out16) {
  const int row = blockIdx.x;
  const int tid = threadIdx.x;
  const size_t base = (size_t)row * E_DIM;
  float v[4];
  float s = 0.f, sq = 0.f;
#pragma unroll
  for (int i = 0; i < 4; i++) {
    const int c = tid + i * 256;
    float x = X[base + c] + Y0[base + c] + Y1[base + c];
    v[i] = x; s += x; sq += x * x;
  }
#pragma unroll
  for (int off = 32; off; off >>= 1) {
    s += __shfl_xor(s, off);
    sq += __shfl_xor(sq, off);
  }
  __shared__ float sh[8];
  const int wave = tid >> 6, lane = tid & 63;
  if (lane == 0) { sh[wave] = s; sh[4 + wave] = sq; }
  __syncthreads();
  s = sh[0] + sh[1] + sh[2] + sh[3];
  sq = sh[4] + sh[5] + sh[6] + sh[7];
  const float mean = s * (1.f / 1024.f);
  const float var = sq * (1.f / 1024.f) - mean * mean;
  const float rstd = rsqrtf(var + 1e-5f);
#pragma unroll
  for (int i = 0; i < 4; i++) {
    const int c = tid + i * 256;
    float y = (v[i] - mean) * rstd * gam[c] + bet[c];
    out32[base + c] = y;
    if (out16) out16[base + c] = f2b(y);
  }
}

// ---------------------------------------------------------------------------
extern "C" void kernel_launch(void* const* d_in, const int* in_sizes, int n_in,
                              void* d_out, int out_size, void* d_ws, size_t ws_size,
                              hipStream_t stream) {
  const float* x   = (const float*)d_in[0];
  const float* Wq  = (const float*)d_in[1];
  const float* bq  = (const float*)d_in[2];
  // d_in[3]=Wk, d_in[4]=bk -- dead code in the reference (scores use Q@V^T)
  const float* Wv  = (const float*)d_in[5];
  const float* bv  = (const float*)d_in[6];
  const float* Wo  = (const float*)d_in[7];
  const float* bo  = (const float*)d_in[8];
  const float* g1  = (const float*)d_in[9];
  const float* b1  = (const float*)d_in[10];
  const float* W1  = (const float*)d_in[11];
  const float* bf1 = (const float*)d_in[12];
  const float* W2  = (const float*)d_in[13];
  const float* bf2 = (const float*)d_in[14];
  const float* g2  = (const float*)d_in[15];
  const float* b2  = (const float*)d_in[16];

  char* w = (char*)d_ws;
  const size_t MB = 1024ull * 1024ull;
  u16*   xb   = (u16*)(w + 0);          //  8MB
  u16*   h1   = (u16*)(w + 8 * MB);     // 32MB
  u16*   qb   = (u16*)(w + 8 * MB);     //  8MB
  u16*   vb   = (u16*)(w + 16 * MB);    //  8MB
  u16*   vtb  = (u16*)(w + 24 * MB);    //  8MB
  u16*   ctxb = (u16*)(w + 32 * MB);    //  8MB
  float* att0 = (float*)(w + 40 * MB);  // 32MB (both Wo partials, contiguous)
  float* ff0  = (float*)(w + 40 * MB);  // 32MB (both FF2 partials, contiguous)
  float* pa   = (float*)(w + 72 * MB);  // 16MB
  u16*   pab  = (u16*)(w + 88 * MB);    //  8MB
  u16*   WqT  = (u16*)(w + 96 * MB);    //  2MB (WqT|WvT contiguous)
  u16*   WvT  = (u16*)(w + 98 * MB);    //  2MB
  u16*   WoT  = (u16*)(w + 100 * MB);   //  2MB
  u16*   W1T  = (u16*)(w + 102 * MB);   //  8MB
  u16*   W2T  = (u16*)(w + 110 * MB);   //  8MB -> 118MB total

  transpose_w<<<dim3(32, 32), 256, 0, stream>>>(Wq, WqT, 1024, 1024);
  transpose_w<<<dim3(32, 32), 256, 0, stream>>>(Wv, WvT, 1024, 1024);
  transpose_w<<<dim3(32, 32), 256, 0, stream>>>(Wo, WoT, 1024, 1024);
  transpose_w<<<dim3(32, 128), 256, 0, stream>>>(W1, W1T, 1024, 4096);
  transpose_w<<<dim3(128, 32), 256, 0, stream>>>(W2, W2T, 4096, 1024);
  f32_to_bf16<<<TOKENS * E_DIM / 4 / 256, 256, 0, stream>>>(x, xb);

  gemm_qv64<<<dim3(32, 32), 256, 0, stream>>>(xb, WqT, bq, bv, qb, vb, 1024);
  transpose_v<<<dim3(32, 32), 256, 0, stream>>>(vb, vtb);
  attn_kernel<<<dim3(32, 32), 128, 0, stream>>>(qb, vb, vtb, ctxb);
  gemm_bt_sk<<<dim3(8, 32, 2), 256, 0, stream>>>(ctxb, WoT, bo, att0, TOKENS, 1024, 1024);
  add_ln3<<<TOKENS, 256, 0, stream>>>(x, att0, att0 + (size_t)TOKENS * 1024, g1, b1, pa, pab);
  gemm_bt<1, 1><<<dim3(32, 32), 256, 0, stream>>>(pab, W1T, bf1, h1, TOKENS, 4096, 1024);
  gemm_bt_sk<<<dim3(8, 32, 2), 256, 0, stream>>>(h1, W2T, bf2, ff0, TOKENS, 1024, 4096);
  add_ln3<<<TOKENS, 256, 0, stream>>>(pa, ff0, ff0 + (size_t)TOKENS * 1024, g2, b2, (float*)d_out, (u16*)nullptr);
}